// Round 7
// baseline (521.669 us; speedup 1.0000x reference)
//
#include <hip/hip_runtime.h>
#include <cstdint>
#include <math.h>

// Transformer block: LN1 -> QKV -> fused MHA (attn probs = output[1]) -> proj+res
//                    -> LN2 -> GELU MLP + res -> output[0]
// GEMMs: fp16 MFMA 16x16x32. qkv/proj/fc2: 128x128 m97-style BK=64 core.
// fc1: 256x256 8-phase pipelined schedule (T2 swizzle, T3/T4 counted vmcnt(6),
// T5 setprio), register-reuse phase pattern 12/4/8/0 ds_reads.

typedef _Float16 f16;
typedef _Float16 f16x4 __attribute__((ext_vector_type(4)));
typedef _Float16 f16x8 __attribute__((ext_vector_type(8)));
typedef float f32x4 __attribute__((ext_vector_type(4)));

#define DEV static __device__ __forceinline__

DEV void gload16(const void* g, void* l) {
  __builtin_amdgcn_global_load_lds(
      (__attribute__((address_space(1))) void*)(uintptr_t)g,
      (__attribute__((address_space(3))) void*)(uintptr_t)l, 16, 0, 0);
}

DEV f32x4 mfma16(f16x8 a, f16x8 b, f32x4 c) {
  return __builtin_amdgcn_mfma_f32_16x16x32_f16(a, b, c, 0, 0, 0);
}

// gelu via Abramowitz-Stegun 7.1.26 erf (|err| <= 1.5e-7)
DEV float gelu_f(float v) {
  const float a = fabsf(v) * 0.70710678118654752f;
  const float t = 1.0f / (1.0f + 0.3275911f * a);
  const float p = t * (0.254829592f + t * (-0.284496736f + t * (1.421413741f +
                  t * (-1.453152027f + t * 1.061405429f))));
  const float e = p * __expf(-a * a);
  const float erfv = v >= 0.f ? (1.f - e) : (e - 1.f);
  return 0.5f * v * (1.0f + erfv);
}

// ===== 128x128 NT GEMM core, BK=64 =====
DEV void nt_core64(const f16* __restrict__ A, const f16* __restrict__ B,
                   size_t lda, size_t ldb, int K, f16* As, f16* Bs,
                   f32x4 acc[4][4])
{
  const int tid  = threadIdx.x;
  const int lane = tid & 63;
  const int w    = tid >> 6;
  const int wm   = (w >> 1) << 6;
  const int wn   = (w & 1) << 6;
  const int frow = lane & 15;
  const int lg   = lane >> 4;

  const int srow0 = w * 32 + (lane >> 3);
  const int scol  = ((lane & 7) ^ ((lane >> 3) & 7)) << 3;
  const f16* Ab = A + (size_t)srow0 * lda + scol;
  const f16* Bb = B + (size_t)srow0 * ldb + scol;
  f16* la = As + w * 2048 + lane * 8;
  f16* lb = Bs + w * 2048 + lane * 8;

  for (int k0 = 0; k0 < K; k0 += 64) {
#pragma unroll
    for (int L = 0; L < 4; ++L)
      gload16(Ab + (size_t)(L * 8) * lda + k0, la + L * 512);
#pragma unroll
    for (int L = 0; L < 4; ++L)
      gload16(Bb + (size_t)(L * 8) * ldb + k0, lb + L * 512);
    __syncthreads();
#pragma unroll
    for (int kc = 0; kc < 2; ++kc) {
      f16x8 af[4], bf[4];
#pragma unroll
      for (int i = 0; i < 4; ++i) {
        const int ra = wm + i * 16 + frow;
        const int rb = wn + i * 16 + frow;
        af[i] = *(const f16x8*)(As + ra * 64 + ((((kc << 2) + lg) ^ (ra & 7)) << 3));
        bf[i] = *(const f16x8*)(Bs + rb * 64 + ((((kc << 2) + lg) ^ (rb & 7)) << 3));
      }
#pragma unroll
      for (int i = 0; i < 4; ++i)
#pragma unroll
        for (int j = 0; j < 4; ++j)
          acc[i][j] = mfma16(af[i], bf[j], acc[i][j]);
    }
    __syncthreads();
  }
}

// ===================== fc1: 256x256 8-phase schedule ======================
// LDS: 2 bufs x 4 slots (As0,As1,Bs0,Bs1) x [128 rows x 64 cols] f16 = 128 KiB.
// Swizzle: elem (r,c) of slot at r*64 + (((c>>3)^(r&7))<<3) + (c&7).
DEV f16* slotp(f16* L, int buf, int s) { return L + buf * 32768 + s * 8192; }

DEV void stg(const f16* base, int koff, f16* sl, int tid) {
  gload16(base + koff, sl + tid * 8);
  gload16(base + koff + (size_t)64 * 1024, sl + 4096 + tid * 8);
}

DEV void rd_a(const f16* S, int base, int ch0, int ch1, f16x8 af[4][2]) {
#pragma unroll
  for (int fi = 0; fi < 4; ++fi) {
    af[fi][0] = *(const f16x8*)(S + base + fi * 1024 + ch0);
    af[fi][1] = *(const f16x8*)(S + base + fi * 1024 + ch1);
  }
}
DEV void rd_b(const f16* S, int base, int ch0, int ch1, f16x8 bf[2][2]) {
#pragma unroll
  for (int fj = 0; fj < 2; ++fj) {
    bf[fj][0] = *(const f16x8*)(S + base + fj * 1024 + ch0);
    bf[fj][1] = *(const f16x8*)(S + base + fj * 1024 + ch1);
  }
}
DEV void mm16(const f16x8 af[4][2], const f16x8 bf[2][2], f32x4 acc[4][2]) {
  __builtin_amdgcn_s_setprio(1);
#pragma unroll
  for (int fi = 0; fi < 4; ++fi)
#pragma unroll
    for (int fj = 0; fj < 2; ++fj) {
      acc[fi][fj] = mfma16(af[fi][0], bf[fj][0], acc[fi][fj]);
      acc[fi][fj] = mfma16(af[fi][1], bf[fj][1], acc[fi][fj]);
    }
  __builtin_amdgcn_s_setprio(0);
}

#define BAR()  __builtin_amdgcn_s_barrier()
#define LGKM0() do { asm volatile("s_waitcnt lgkmcnt(0)" ::: "memory"); \
                     __builtin_amdgcn_sched_barrier(0); } while (0)
#define VM6()  do { asm volatile("s_waitcnt vmcnt(6)" ::: "memory"); } while (0)
#define VM0()  do { asm volatile("s_waitcnt vmcnt(0)" ::: "memory"); } while (0)
#define SCB()  __builtin_amdgcn_sched_barrier(0)

__global__ __launch_bounds__(512) void k_fc18(const f16* __restrict__ xn,
                                              const f16* __restrict__ wf,
                                              const float* __restrict__ bfc1,
                                              f16* __restrict__ hb)
{
  extern __shared__ __align__(16) f16 L[];
  const int flat = blockIdx.x;                 // 512 blocks
  const int local = flat >> 3;
  const int bm = (flat & 7) * 4 + (local & 3); // XCD-chunked, bijective
  const int bn = local >> 2;
  const int tid = threadIdx.x, lane = tid & 63, w = tid >> 6;
  const int lr = lane & 15, lg = lane >> 4;

  const int rl = tid >> 3;
  const int gc = ((tid & 7) ^ (rl & 7)) << 3;
  const f16* a0 = xn + (size_t)(bm * 256 + rl) * 1024 + gc;
  const f16* a1 = a0 + (size_t)128 * 1024;
  const f16* b0 = wf + (size_t)(bn * 256 + rl) * 1024 + gc;
  const f16* b1 = b0 + (size_t)128 * 1024;

  const int base_ar = ((((w >> 2) << 6) + lr) << 6);
  const int base_br = ((((w & 3) << 5) + lr) << 6);
  const int sx = lr & 7;
  const int ch0 = ((0 + lg) ^ sx) << 3;
  const int ch1 = ((4 + lg) ^ sx) << 3;

  f32x4 acc0[4][2] = {}, acc1[4][2] = {}, acc2[4][2] = {}, acc3[4][2] = {};
  f16x8 af[4][2], bfA[2][2], bfB[2][2];

  // prologue: tile0 all halves + tile1 As0,Bs0 (issue order matters)
  stg(a0, 0,  slotp(L, 0, 0), tid);
  stg(b0, 0,  slotp(L, 0, 2), tid);
  stg(b1, 0,  slotp(L, 0, 3), tid);
  stg(a1, 0,  slotp(L, 0, 1), tid);
  stg(a0, 64, slotp(L, 1, 0), tid);
  stg(b0, 64, slotp(L, 1, 2), tid);
  asm volatile("s_waitcnt vmcnt(4)" ::: "memory");   // tile0's 8 loads done
  BAR(); SCB();

  const int NT = 16;
  for (int t = 0; t < NT; ++t) {
    const int p = t & 1, nb = p ^ 1;
    const f16* As0 = slotp(L, p, 0);
    const f16* As1 = slotp(L, p, 1);
    const f16* Bs0 = slotp(L, p, 2);
    const f16* Bs1 = slotp(L, p, 3);
    const bool s1 = t < NT - 1, s2 = t < NT - 2;
    const int k1 = (t + 1) * 64, k2 = (t + 2) * 64;

    // ---- ph1: read af<-As0, bfA<-Bs0; stage Bs1(t+1); mfma (a0,b0)
    rd_a(As0, base_ar, ch0, ch1, af);
    rd_b(Bs0, base_br, ch0, ch1, bfA);
    if (s1) stg(b1, k1, slotp(L, nb, 3), tid);
    BAR(); LGKM0();
    mm16(af, bfA, acc0);
    if (s2) VM6();
    BAR(); SCB();

    // ---- ph2: read bfB<-Bs1; stage As1(t+1); mfma (a0,b1)
    rd_b(Bs1, base_br, ch0, ch1, bfB);
    if (s1) stg(a1, k1, slotp(L, nb, 1), tid);
    BAR(); LGKM0();
    mm16(af, bfB, acc1);
    if (s2) VM6();
    BAR(); SCB();

    // ---- ph3: read af<-As1; stage As0(t+2); mfma (a1,b1)
    rd_a(As1, base_ar, ch0, ch1, af);
    if (s2) stg(a0, k2, slotp(L, p, 0), tid);
    BAR(); LGKM0();
    mm16(af, bfB, acc3);
    if (s2) VM6();
    BAR(); SCB();

    // ---- ph4: no reads; stage Bs0(t+2); mfma (a1,b0)
    if (s2) stg(b0, k2, slotp(L, p, 2), tid);
    BAR(); SCB();
    mm16(af, bfA, acc2);
    if (s2) VM6();
    else if (s1) VM0();      // t == NT-2: drain before final tile
    BAR(); SCB();
  }

  // epilogue
  const int r00 = bm * 256 + ((w >> 2) << 6) + (lg << 2);
  const int c00 = bn * 256 + ((w & 3) << 5) + lr;
#pragma unroll
  for (int a = 0; a < 2; ++a)
#pragma unroll
    for (int b = 0; b < 2; ++b) {
      const f32x4 (&A)[4][2] = (a == 0) ? (b == 0 ? acc0 : acc1)
                                        : (b == 0 ? acc2 : acc3);
#pragma unroll
      for (int fj = 0; fj < 2; ++fj) {
        const int c = c00 + b * 128 + fj * 16;
        const float bias = bfc1[c];
#pragma unroll
        for (int fi = 0; fi < 4; ++fi)
#pragma unroll
          for (int e = 0; e < 4; ++e) {
            const int r = r00 + a * 128 + fi * 16 + e;
            hb[(size_t)r * 4096 + c] = (f16)gelu_f(A[fi][fj][e] + bias);
          }
      }
    }
}

// ------- fused: fp32->fp16 weight convert (blocks 0..12287) + LN1 (rest) ----
__global__ __launch_bounds__(256) void k_cvt_ln(const float* __restrict__ s0,
                                                const float* __restrict__ s1,
                                                const float* __restrict__ s2,
                                                const float* __restrict__ s3,
                                                f16* __restrict__ wout,
                                                const float* __restrict__ xin,
                                                const float* __restrict__ g,
                                                const float* __restrict__ bb,
                                                f16* __restrict__ xnout)
{
  __shared__ float red[8];
  const int tid = threadIdx.x;
  if (blockIdx.x < 12288) {
    const int i = blockIdx.x * 256 + tid;
    const float* src;
    int off;
    if (i < 786432)       { src = s0; off = 0; }
    else if (i < 1048576) { src = s1; off = 786432; }
    else if (i < 2097152) { src = s2; off = 1048576; }
    else                  { src = s3; off = 2097152; }
    const float4 f = ((const float4*)src)[i - off];
    f16x4 o; o[0] = (f16)f.x; o[1] = (f16)f.y; o[2] = (f16)f.z; o[3] = (f16)f.w;
    ((f16x4*)wout)[i] = o;
    return;
  }
  const size_t row = blockIdx.x - 12288;
  const float4 v = ((const float4*)(xin + row * 1024))[tid];
  float s  = v.x + v.y + v.z + v.w;
  float sq = v.x * v.x + v.y * v.y + v.z * v.z + v.w * v.w;
#pragma unroll
  for (int off = 32; off > 0; off >>= 1) { s += __shfl_xor(s, off); sq += __shfl_xor(sq, off); }
  if ((tid & 63) == 0) { red[tid >> 6] = s; red[4 + (tid >> 6)] = sq; }
  __syncthreads();
  s  = red[0] + red[1] + red[2] + red[3];
  sq = red[4] + red[5] + red[6] + red[7];
  const float mu = s * (1.0f / 1024.0f);
  const float rs = rsqrtf(sq * (1.0f / 1024.0f) - mu * mu + 1e-5f);
  const float4 gg = ((const float4*)g)[tid];
  const float4 bv = ((const float4*)bb)[tid];
  f16x4 o;
  o[0] = (f16)((v.x - mu) * rs * gg.x + bv.x);
  o[1] = (f16)((v.y - mu) * rs * gg.y + bv.y);
  o[2] = (f16)((v.z - mu) * rs * gg.z + bv.z);
  o[3] = (f16)((v.w - mu) * rs * gg.w + bv.w);
  ((f16x4*)(xnout + row * 1024))[tid] = o;
}

// ---------------- LayerNorm (1024 cols, 1 row/block) ----------------
__global__ __launch_bounds__(256) void k_ln(const float* __restrict__ xin,
                                            const float* __restrict__ g,
                                            const float* __restrict__ bb,
                                            f16* __restrict__ out)
{
  __shared__ float red[8];
  const int tid = threadIdx.x;
  const size_t row = blockIdx.x;
  const float4 v = ((const float4*)(xin + row * 1024))[tid];
  float s  = v.x + v.y + v.z + v.w;
  float sq = v.x * v.x + v.y * v.y + v.z * v.z + v.w * v.w;
#pragma unroll
  for (int off = 32; off > 0; off >>= 1) { s += __shfl_xor(s, off); sq += __shfl_xor(sq, off); }
  if ((tid & 63) == 0) { red[tid >> 6] = s; red[4 + (tid >> 6)] = sq; }
  __syncthreads();
  s  = red[0] + red[1] + red[2] + red[3];
  sq = red[4] + red[5] + red[6] + red[7];
  const float mu = s * (1.0f / 1024.0f);
  const float rs = rsqrtf(sq * (1.0f / 1024.0f) - mu * mu + 1e-5f);
  const float4 gg = ((const float4*)g)[tid];
  const float4 bv = ((const float4*)bb)[tid];
  f16x4 o;
  o[0] = (f16)((v.x - mu) * rs * gg.x + bv.x);
  o[1] = (f16)((v.y - mu) * rs * gg.y + bv.y);
  o[2] = (f16)((v.z - mu) * rs * gg.z + bv.z);
  o[3] = (f16)((v.w - mu) * rs * gg.w + bv.w);
  ((f16x4*)(out + row * 1024))[tid] = o;
}

// ---------------- QKV GEMM: [8192,1024] x [3072,1024]^T ----------------
__global__ __launch_bounds__(256) void k_qkv(const f16* __restrict__ xn,
                                             const f16* __restrict__ wq,
                                             f16* __restrict__ qb, f16* __restrict__ kb,
                                             f16* __restrict__ vT)
{
  __shared__ __align__(16) f16 As[8192], Bs[8192];
  f32x4 acc[4][4] = {};
  const int flat = blockIdx.x;                 // 1536 blocks
  const int local = flat >> 3;
  const int bm = (flat & 7) * 8 + (local & 7); // XCD-chunked, bijective
  const int bn = local >> 3;
  nt_core64(xn + (size_t)bm * 128 * 1024, wq + (size_t)bn * 128 * 1024,
            1024, 1024, 1024, As, Bs, acc);
  const int tid = threadIdx.x, lane = tid & 63, w = tid >> 6;
  const int r0 = bm * 128 + ((w >> 1) << 6) + ((lane >> 4) << 2);
  const int c0 = bn * 128 + ((w & 1) << 6);
  const int sec = (bn * 128) >> 10;
#pragma unroll
  for (int i = 0; i < 4; ++i) {
#pragma unroll
    for (int j = 0; j < 4; ++j) {
      const int o = c0 + j * 16 + (lane & 15);
      const int h = (o & 1023) >> 6, d = o & 63;
#pragma unroll
      for (int e = 0; e < 4; ++e) {
        const int m = r0 + i * 16 + e;
        const int b = m >> 10, n = m & 1023;
        const int bh = (b << 4) + h;
        const f16 val = (f16)acc[i][j][e];
        if (sec == 0)      qb[((size_t)bh * 1024 + n) * 64 + d] = val;
        else if (sec == 1) kb[((size_t)bh * 1024 + n) * 64 + d] = val;
        else               vT[((size_t)bh * 64 + d) * 1024 + n] = val;
      }
    }
  }
}

// ---------------- fused attention ----------------
__global__ __launch_bounds__(256) void k_attn(const f16* __restrict__ qb,
                                              const f16* __restrict__ kb,
                                              const f16* __restrict__ vT,
                                              float* __restrict__ attn,
                                              f16* __restrict__ y2)
{
  __shared__ __align__(16) f16 P[32 * 1024];   // exactly 64 KB
  const int tid = threadIdx.x, lane = tid & 63, w = tid >> 6;
  const int lr = lane & 15, lg = lane >> 4;
  const int flat = blockIdx.y * 32 + blockIdx.x;
  const int id2 = (flat & 7) * 512 + (flat >> 3);
  const int bh = id2 >> 5;
  const int m0 = (id2 & 31) * 32;
  const f16* Qb = qb + ((size_t)bh << 16);
  const f16* Kb = kb + ((size_t)bh << 16);
  const f16* Vt = vT + ((size_t)bh << 16);

  f16x8 qf[2][2];
#pragma unroll
  for (int i = 0; i < 2; ++i)
#pragma unroll
    for (int ks = 0; ks < 2; ++ks)
      qf[i][ks] = *(const f16x8*)(Qb + (size_t)(m0 + i * 16 + lr) * 64 + ks * 32 + lg * 8);

  for (int cc = 0; cc < 4; ++cc) {
    const int cb = (w << 8) + (cc << 6);
    f16x8 bf[4][2];
#pragma unroll
    for (int j = 0; j < 4; ++j)
#pragma unroll
      for (int ks = 0; ks < 2; ++ks)
        bf[j][ks] = *(const f16x8*)(Kb + (size_t)(cb + j * 16 + lr) * 64 + ks * 32 + lg * 8);
    f32x4 acc[2][4] = {};
#pragma unroll
    for (int i = 0; i < 2; ++i)
#pragma unroll
      for (int j = 0; j < 4; ++j) {
        acc[i][j] = mfma16(qf[i][0], bf[j][0], acc[i][j]);
        acc[i][j] = mfma16(qf[i][1], bf[j][1], acc[i][j]);
      }
#pragma unroll
    for (int i = 0; i < 2; ++i)
#pragma unroll
      for (int j = 0; j < 4; ++j)
#pragma unroll
        for (int e = 0; e < 4; ++e) {
          const int r = i * 16 + (lg << 2) + e;
          const int c = cb + j * 16 + lr;
          P[(r << 10) + (((c >> 3) ^ (r & 7)) << 3) + (c & 7)] = (f16)(acc[i][j][e] * 0.125f);
        }
  }
  __syncthreads();

  const int r2 = tid >> 3;
  f16* Prow = P + (r2 << 10);
  const int rx = r2 & 7;
  f16x8 vv[16];
  float mrow = -1e30f;
#pragma unroll
  for (int q = 0; q < 16; ++q) {
    const int c = (tid & 7) + (q << 3);
    vv[q] = *(const f16x8*)(Prow + ((c ^ rx) << 3));
#pragma unroll
    for (int e = 0; e < 8; ++e) mrow = fmaxf(mrow, (float)vv[q][e]);
  }
  mrow = fmaxf(mrow, __shfl_xor(mrow, 1));
  mrow = fmaxf(mrow, __shfl_xor(mrow, 2));
  mrow = fmaxf(mrow, __shfl_xor(mrow, 4));
  float ssum = 0.f;
#pragma unroll
  for (int q = 0; q < 16; ++q) {
#pragma unroll
    for (int e = 0; e < 8; ++e) {
      const float ev = __expf((float)vv[q][e] - mrow);
      ssum += ev;
      vv[q][e] = (f16)ev;
    }
  }
  ssum += __shfl_xor(ssum, 1);
  ssum += __shfl_xor(ssum, 2);
  ssum += __shfl_xor(ssum, 4);
  const float inv = 1.0f / ssum;
  float* Aout = attn + ((size_t)bh << 20) + ((size_t)(m0 + r2) << 10);
#pragma unroll
  for (int q = 0; q < 16; ++q) {
    const int c = (tid & 7) + (q << 3);
    f16x8 nv;
    f32x4 o0, o1;
    o0[0] = (float)vv[q][0] * inv; o0[1] = (float)vv[q][1] * inv;
    o0[2] = (float)vv[q][2] * inv; o0[3] = (float)vv[q][3] * inv;
    o1[0] = (float)vv[q][4] * inv; o1[1] = (float)vv[q][5] * inv;
    o1[2] = (float)vv[q][6] * inv; o1[3] = (float)vv[q][7] * inv;
#pragma unroll
    for (int e = 0; e < 8; ++e) nv[e] = (f16)((float)vv[q][e] * inv);
    __builtin_nontemporal_store(o0, (f32x4*)(Aout + (c << 3)));
    __builtin_nontemporal_store(o1, (f32x4*)(Aout + (c << 3)) + 1);
    *(f16x8*)(Prow + ((c ^ rx) << 3)) = nv;
  }
  __syncthreads();

  const int dc = w << 4;
  f32x4 acc2[2] = {};
#pragma unroll 4
  for (int k0 = 0; k0 < 1024; k0 += 32) {
    const f16x8 bf = *(const f16x8*)(Vt + (size_t)(dc + lr) * 1024 + k0 + lg * 8);
#pragma unroll
    for (int i = 0; i < 2; ++i) {
      const int ra = i * 16 + lr;
      const int ch = (k0 >> 3) + lg;
      const f16x8 af = *(const f16x8*)(P + (ra << 10) + ((ch ^ (ra & 7)) << 3));
      acc2[i] = mfma16(af, bf, acc2[i]);
    }
  }
  const int b = bh >> 4, h = bh & 15;
#pragma unroll
  for (int i = 0; i < 2; ++i)
#pragma unroll
    for (int e = 0; e < 4; ++e) {
      const int rloc = i * 16 + (lg << 2) + e;
      y2[(size_t)(b * 1024 + m0 + rloc) * 1024 + (h << 6) + dc + lr] = (f16)acc2[i][e];
    }
}

// ---------------- proj: xmid = y2 @ wproj^T + bproj + x ----------------
__global__ __launch_bounds__(256) void k_proj(const f16* __restrict__ y2,
                                              const f16* __restrict__ wp,
                                              const float* __restrict__ bproj,
                                              const float* __restrict__ x,
                                              float* __restrict__ xmid)
{
  __shared__ __align__(16) f16 As[8192], Bs[8192];
  f32x4 acc[4][4] = {};
  const int flat = blockIdx.x;                 // 512 blocks
  const int local = flat >> 3;
  const int bm = (flat & 7) * 8 + (local & 7);
  const int bn = local >> 3;
  nt_core64(y2 + (size_t)bm * 128 * 1024, wp + (size_t)bn * 128 * 1024,
            1024, 1024, 1024, As, Bs, acc);
  const int tid = threadIdx.x, lane = tid & 63, w = tid >> 6;
  const int r0 = bm * 128 + ((w >> 1) << 6) + ((lane >> 4) << 2);
  const int c0 = bn * 128 + ((w & 1) << 6) + (lane & 15);
#pragma unroll
  for (int i = 0; i < 4; ++i)
#pragma unroll
    for (int j = 0; j < 4; ++j) {
      const int c = c0 + j * 16;
      const float bias = bproj[c];
#pragma unroll
      for (int e = 0; e < 4; ++e) {
        const size_t idx = (size_t)(r0 + i * 16 + e) * 1024 + c;
        xmid[idx] = acc[i][j][e] + bias + x[idx];
      }
    }
}

// ---------------- fc2: out = h @ wfc2^T + bfc2 + xmid ----------------
__global__ __launch_bounds__(256) void k_fc2(const f16* __restrict__ hb,
                                             const f16* __restrict__ wf,
                                             const float* __restrict__ bfc2,
                                             const float* __restrict__ xmid,
                                             float* __restrict__ out)
{
  __shared__ __align__(16) f16 As[8192], Bs[8192];
  f32x4 acc[4][4] = {};
  const int flat = blockIdx.x;                 // 512 blocks
  const int local = flat >> 3;
  const int bm = (flat & 7) * 8 + (local & 7);
  const int bn = local >> 3;
  nt_core64(hb + (size_t)bm * 128 * 4096, wf + (size_t)bn * 128 * 4096,
            4096, 4096, 4096, As, Bs, acc);
  const int tid = threadIdx.x, lane = tid & 63, w = tid >> 6;
  const int r0 = bm * 128 + ((w >> 1) << 6) + ((lane >> 4) << 2);
  const int c0 = bn * 128 + ((w & 1) << 6) + (lane & 15);
#pragma unroll
  for (int i = 0; i < 4; ++i)
#pragma unroll
    for (int j = 0; j < 4; ++j) {
      const int c = c0 + j * 16;
      const float bias = bfc2[c];
#pragma unroll
      for (int e = 0; e < 4; ++e) {
        const size_t idx = (size_t)(r0 + i * 16 + e) * 1024 + c;
        out[idx] = acc[i][j][e] + bias + xmid[idx];
      }
    }
}

extern "C" void kernel_launch(void* const* d_in, const int* in_sizes, int n_in,
                              void* d_out, int out_size, void* d_ws, size_t ws_size,
                              hipStream_t stream)
{
  const float* x     = (const float*)d_in[0];
  const float* ln1g  = (const float*)d_in[1];
  const float* ln1b  = (const float*)d_in[2];
  const float* wqkv  = (const float*)d_in[3];
  const float* wproj = (const float*)d_in[4];
  const float* bproj = (const float*)d_in[5];
  const float* ln2g  = (const float*)d_in[6];
  const float* ln2b  = (const float*)d_in[7];
  const float* wfc1  = (const float*)d_in[8];
  const float* bfc1  = (const float*)d_in[9];
  const float* wfc2  = (const float*)d_in[10];
  const float* bfc2  = (const float*)d_in[11];

  char* ws = (char*)d_ws;
  f16* wqkv_h  = (f16*)(ws);                    //  6 MB  (contiguous cvt dest)
  f16* wproj_h = (f16*)(ws + 6291456);          //  2 MB
  f16* wfc1_h  = (f16*)(ws + 8388608);          //  8 MB
  f16* wfc2_h  = (f16*)(ws + 16777216);         //  8 MB
  f16* xn      = (f16*)(ws + 25165824);         // 16 MB (xn1, reused as xn2)
  f16* qb      = (f16*)(ws + 41943040);         // 16 MB
  f16* kb      = (f16*)(ws + 58720256);         // 16 MB
  f16* vT      = (f16*)(ws + 75497472);         // 16 MB
  f16* y2      = (f16*)(ws + 92274688);         // 16 MB
  float* xmid  = (float*)(ws + 109051904);      // 32 MB
  f16* hb      = (f16*)(ws + 41943040);         // 64 MB, aliases qb..y2 (dead by fc1)

  float* out_x = (float*)d_out;
  float* attn  = (float*)d_out + 8388608;

  hipFuncSetAttribute((const void*)k_fc18, hipFuncAttributeMaxDynamicSharedMemorySize, 131072);

  k_cvt_ln<<<12288 + 8192, 256, 0, stream>>>(wqkv, wproj, wfc1, wfc2, wqkv_h,
                                             x, ln1g, ln1b, xn);
  k_qkv<<<1536, 256, 0, stream>>>(xn, wqkv_h, qb, kb, vT);
  k_attn<<<dim3(32, 128), 256, 0, stream>>>(qb, kb, vT, attn, y2);
  k_proj<<<512, 256, 0, stream>>>(y2, wproj_h, bproj, x, xmid);
  k_ln<<<8192, 256, 0, stream>>>(xmid, ln2g, ln2b, xn);
  k_fc18<<<512, 512, 131072, stream>>>(xn, wfc1_h, bfc1, hb);
  k_fc2<<<512, 256, 0, stream>>>(hb, wfc2_h, bfc2, xmid, out_x);
}